// Round 2
// baseline (1348.351 us; speedup 1.0000x reference)
//
#include <hip/hip_runtime.h>

// Problem constants (fixed by the reference): B=8, C=256, H=W=64, dg=4, K=3x3.
#define B_   8
#define C_   256
#define HW_  4096
#define DG_  4
#define CG_  64
#define OC_  72      // offset channels = dg*2*9
#define PC_  34      // pred_init channels
#define CLS_OFF (B_ * C_ * HW_)   // 8388608 floats, start of cls output

// ---------------------------------------------------------------------------
// Kernel 1: offset[b,o,hw] = sum_c pred[b,c,hw] * w_off[o,c]   (72x34 1x1 conv)
// ---------------------------------------------------------------------------
__global__ __launch_bounds__(256)
void offset_kernel(const float* __restrict__ pred, const float* __restrict__ wo,
                   float* __restrict__ offset) {
  const int p  = blockIdx.x * 256 + threadIdx.x;   // 0..32767 = b*4096 + hw
  const int b  = p >> 12;
  const int hw = p & 4095;
  const float* pp = pred + (size_t)b * PC_ * HW_ + hw;
  float v[PC_];
#pragma unroll
  for (int i = 0; i < PC_; ++i) v[i] = pp[(size_t)i * HW_];
  float* op = offset + (size_t)b * OC_ * HW_ + hw;
  for (int o = 0; o < OC_; ++o) {
    float s = 0.f;
#pragma unroll
    for (int i = 0; i < PC_; ++i) s = fmaf(v[i], wo[o * PC_ + i], s);
    op[(size_t)o * HW_] = s;
  }
}

// ---------------------------------------------------------------------------
// Kernel 2: repack weights so the GEMM A-tile loads coalesce.
// wT[map][(g*9+k)*64 + c][o] = w_map[o][(g*64+c)*9 + k]
// ---------------------------------------------------------------------------
__global__ __launch_bounds__(256)
void transpose_w_kernel(const float* __restrict__ w_reg,
                        const float* __restrict__ w_cls,
                        float* __restrict__ wT) {
  const int idx  = blockIdx.x * 256 + threadIdx.x;  // 0 .. 2*2304*256-1
  const int o    = idx & 255;
  const int rest = idx >> 8;            // map*2304 + kk2
  const int kk2  = rest % 2304;
  const int map  = rest / 2304;
  const int g = kk2 / 576, r = kk2 % 576, k = r / 64, c = r % 64;
  const float* src = map ? w_cls : w_reg;
  wT[idx] = src[o * 2304 + (g * 64 + c) * 9 + k];
}

// ---------------------------------------------------------------------------
// Kernel 3: fused deformable-conv implicit GEMM for BOTH feature maps.
// Block = (b, 32-pixel tile). Computes out[2][256][32] tile.
// K-loop: g(4) x k(9) x c-chunk(4 of 16). Bilinear params computed once per
// (g,k,pixel), reused across 64 channels and both maps.
// launch_bounds(256,3): 3 blocks/CU (block = 4 waves = 1 wave/SIMD), VGPR
// budget ~170 -> no spill risk with 64 acc regs, +50% waves to hide syncs.
// ---------------------------------------------------------------------------
__global__ __launch_bounds__(256, 3)
void deform_main(const float* __restrict__ xreg, const float* __restrict__ xcls,
                 const float* __restrict__ offset, const float* __restrict__ wT,
                 float* __restrict__ out) {
  __shared__ float sA[2][16][256];   // [map][c][o]      32 KiB
  __shared__ float sB[2][16][32];    // [map][c][px]      4 KiB
  __shared__ int   sI[4][32];        // corner indices  0.5 KiB
  __shared__ float sW[4][32];        // corner weights  0.5 KiB

  const int b   = blockIdx.y;
  const int px0 = blockIdx.x * 32;
  const int t   = threadIdx.x;
  const int tx  = t & 7,  ty  = t >> 3;
  const int tx4 = tx * 4, ty8 = ty * 8;

  float accR[8][4], accC[8][4];
#pragma unroll
  for (int o = 0; o < 8; ++o)
#pragma unroll
    for (int p = 0; p < 4; ++p) { accR[o][p] = 0.f; accC[o][p] = 0.f; }

  const float4* wT4 = reinterpret_cast<const float4*>(wT);

  for (int g = 0; g < DG_; ++g) {
    for (int k = 0; k < 9; ++k) {
      // ---- bilinear params for this (g,k) over the 32 pixels ----
      if (t < 32) {
        const int hw = px0 + t;
        const int y = hw >> 6, x = hw & 63;
        const int ch = (g * 9 + k) * 2;
        const float oy = offset[((size_t)b * OC_ + ch) * HW_ + hw];
        const float ox = offset[((size_t)b * OC_ + ch + 1) * HW_ + hw];
        const float py  = (float)(y + (k / 3) - 1) + oy;
        const float pxx = (float)(x + (k % 3) - 1) + ox;
        const float y0f = floorf(py), x0f = floorf(pxx);
        const float tyf = py - y0f,  txf = pxx - x0f;
        const int y0 = (int)y0f, x0 = (int)x0f;
        const int y1 = y0 + 1,   x1 = x0 + 1;
        const bool vy0 = (y0 >= 0) & (y0 <= 63), vy1 = (y1 >= 0) & (y1 <= 63);
        const bool vx0 = (x0 >= 0) & (x0 <= 63), vx1 = (x1 >= 0) & (x1 <= 63);
        const int cy0 = min(max(y0, 0), 63), cy1 = min(max(y1, 0), 63);
        const int cx0 = min(max(x0, 0), 63), cx1 = min(max(x1, 0), 63);
        sI[0][t] = cy0 * 64 + cx0;  sW[0][t] = (vy0 && vx0) ? (1.f - tyf) * (1.f - txf) : 0.f;
        sI[1][t] = cy0 * 64 + cx1;  sW[1][t] = (vy0 && vx1) ? (1.f - tyf) * txf         : 0.f;
        sI[2][t] = cy1 * 64 + cx0;  sW[2][t] = (vy1 && vx0) ? tyf * (1.f - txf)         : 0.f;
        sI[3][t] = cy1 * 64 + cx1;  sW[3][t] = (vy1 && vx1) ? tyf * txf                 : 0.f;
      }
      __syncthreads();

      for (int cc = 0; cc < 4; ++cc) {
        // ---- stage A: weights for (g,k,cc), 2 maps x 16 c x 256 o ----
        const int kk2base = (g * 9 + k) * 64 + cc * 16;
#pragma unroll
        for (int j = 0; j < 8; ++j) {
          const int f = j * 256 + t;            // 0..2047 float4 slots
          const int map = f >> 10, rem = f & 1023;
          const int c = rem >> 6, o4 = rem & 63;
          const float4 v = wT4[((size_t)map * 2304 + kk2base + c) * 64 + o4];
          *reinterpret_cast<float4*>(&sA[map][c][o4 * 4]) = v;
        }
        // ---- stage B: bilinear samples, 2 maps x 16 c x 32 px ----
        {
          const int ppx = t & 31;
          const int c2  = (t >> 5) * 2;
          const int i0 = sI[0][ppx], i1 = sI[1][ppx], i2 = sI[2][ppx], i3 = sI[3][ppx];
          const float w0 = sW[0][ppx], w1 = sW[1][ppx], w2 = sW[2][ppx], w3 = sW[3][ppx];
#pragma unroll
          for (int dc = 0; dc < 2; ++dc) {
            const int c = c2 + dc;
            const size_t base = ((size_t)((b * DG_ + g) * CG_ + cc * 16 + c)) * HW_;
            const float vr = w0 * xreg[base + i0] + w1 * xreg[base + i1]
                           + w2 * xreg[base + i2] + w3 * xreg[base + i3];
            const float vc = w0 * xcls[base + i0] + w1 * xcls[base + i1]
                           + w2 * xcls[base + i2] + w3 * xcls[base + i3];
            sB[0][c][ppx] = vr;
            sB[1][c][ppx] = vc;
          }
        }
        __syncthreads();

        // ---- GEMM micro-tile: 8 o x 4 px x 2 maps per thread ----
#pragma unroll
        for (int c = 0; c < 16; ++c) {
          const float4 br  = *reinterpret_cast<const float4*>(&sB[0][c][tx4]);
          const float4 bc  = *reinterpret_cast<const float4*>(&sB[1][c][tx4]);
          const float4 ar0 = *reinterpret_cast<const float4*>(&sA[0][c][ty8]);
          const float4 ar1 = *reinterpret_cast<const float4*>(&sA[0][c][ty8 + 4]);
          const float4 ac0 = *reinterpret_cast<const float4*>(&sA[1][c][ty8]);
          const float4 ac1 = *reinterpret_cast<const float4*>(&sA[1][c][ty8 + 4]);
          const float a_r[8] = {ar0.x, ar0.y, ar0.z, ar0.w, ar1.x, ar1.y, ar1.z, ar1.w};
          const float a_c[8] = {ac0.x, ac0.y, ac0.z, ac0.w, ac1.x, ac1.y, ac1.z, ac1.w};
          const float b_r[4] = {br.x, br.y, br.z, br.w};
          const float b_c[4] = {bc.x, bc.y, bc.z, bc.w};
#pragma unroll
          for (int o = 0; o < 8; ++o)
#pragma unroll
            for (int p = 0; p < 4; ++p) {
              accR[o][p] = fmaf(a_r[o], b_r[p], accR[o][p]);
              accC[o][p] = fmaf(a_c[o], b_c[p], accC[o][p]);
            }
        }
        __syncthreads();
      }
    }
  }

  // ---- epilogue: ReLU + coalesced float4 stores ----
  const size_t obase = ((size_t)b * C_ + ty8) * HW_ + px0 + tx4;
#pragma unroll
  for (int o = 0; o < 8; ++o) {
    float4 vr, vc;
    vr.x = fmaxf(accR[o][0], 0.f); vr.y = fmaxf(accR[o][1], 0.f);
    vr.z = fmaxf(accR[o][2], 0.f); vr.w = fmaxf(accR[o][3], 0.f);
    vc.x = fmaxf(accC[o][0], 0.f); vc.y = fmaxf(accC[o][1], 0.f);
    vc.z = fmaxf(accC[o][2], 0.f); vc.w = fmaxf(accC[o][3], 0.f);
    *reinterpret_cast<float4*>(&out[obase + (size_t)o * HW_]) = vr;
    *reinterpret_cast<float4*>(&out[CLS_OFF + obase + (size_t)o * HW_]) = vc;
  }
}

// ---------------------------------------------------------------------------
extern "C" void kernel_launch(void* const* d_in, const int* in_sizes, int n_in,
                              void* d_out, int out_size, void* d_ws, size_t ws_size,
                              hipStream_t stream) {
  const float* reg_feat = (const float*)d_in[0];   // [8,256,64,64]
  const float* cls_feat = (const float*)d_in[1];   // [8,256,64,64]
  const float* pred     = (const float*)d_in[2];   // [8,34,64,64]
  const float* w_off    = (const float*)d_in[3];   // [72,34]
  const float* w_reg    = (const float*)d_in[4];   // [256,256,3,3]
  const float* w_cls    = (const float*)d_in[5];   // [256,256,3,3]
  float* outp = (float*)d_out;

  // ws layout: offset (2,359,296 f) | wT (1,179,648 f)  -> ~13.5 MB total
  float* offset = (float*)d_ws;
  float* wT     = offset + (size_t)B_ * OC_ * HW_;

  offset_kernel<<<dim3((B_ * HW_) / 256), 256, 0, stream>>>(pred, w_off, offset);
  transpose_w_kernel<<<dim3((2 * 2304 * 256) / 256), 256, 0, stream>>>(w_reg, w_cls, wT);
  deform_main<<<dim3(HW_ / 32, B_), dim3(256), 0, stream>>>(reg_feat, cls_feat,
                                                            offset, wT, outp);
}

// Round 3
// 637.482 us; speedup vs baseline: 2.1151x; 2.1151x over previous
//
#include <hip/hip_runtime.h>

// Problem constants: B=8, C=256, H=W=64, dg=4, K=3x3.
#define B_   8
#define C_   256
#define HW_  4096
#define OC_  72      // offset channels = dg*2*9
#define PC_  34      // pred_init channels
#define CLS_OFF (B_ * C_ * HW_)

typedef __attribute__((ext_vector_type(8))) short short8v;  // 8 bf16 = 4 VGPR
typedef __attribute__((ext_vector_type(4))) float f32x4;

__device__ __forceinline__ ushort f2bf(float f) {           // fp32 -> bf16 RNE
  uint u = __float_as_uint(f);
  return (ushort)((u + 0x7fffu + ((u >> 16) & 1u)) >> 16);
}
__device__ __forceinline__ float bf2f(ushort h) {
  return __uint_as_float(((uint)h) << 16);
}

// ---------------------------------------------------------------------------
// Kernel 1: offset[b,o,hw] = sum_c pred[b,c,hw] * w_off[o,c]
// ---------------------------------------------------------------------------
__global__ __launch_bounds__(256)
void offset_kernel(const float* __restrict__ pred, const float* __restrict__ wo,
                   float* __restrict__ offset) {
  const int p  = blockIdx.x * 256 + threadIdx.x;
  const int b  = p >> 12;
  const int hw = p & 4095;
  const float* pp = pred + (size_t)b * PC_ * HW_ + hw;
  float v[PC_];
#pragma unroll
  for (int i = 0; i < PC_; ++i) v[i] = pp[(size_t)i * HW_];
  float* op = offset + (size_t)b * OC_ * HW_ + hw;
  for (int o = 0; o < OC_; ++o) {
    float s = 0.f;
#pragma unroll
    for (int i = 0; i < PC_; ++i) s = fmaf(v[i], wo[o * PC_ + i], s);
    op[(size_t)o * HW_] = s;
  }
}

// ---------------------------------------------------------------------------
// Kernel 2: split weights into bf16 hi/lo, laid out in exact MFMA A-fragment
// order so deform loads fragments directly from global memory:
// wpk[(map*36+s)*2+kk][hl][mf16][lane][j]  (16384 elems per (map,s,kk))
//   o = mf16*16 + (lane&15);  c = kk*32 + (lane>>4)*8 + j;  g=s/9, kp=s%9
// ---------------------------------------------------------------------------
__global__ __launch_bounds__(256)
void repack_w(const float* __restrict__ w_reg, const float* __restrict__ w_cls,
              ushort* __restrict__ wpk) {
  const int tid = blockIdx.x * 256 + threadIdx.x;   // 147456 total
  const int l   = tid & 63;
  const int mf  = (tid >> 6) & 15;
  int rest = tid >> 10;
  const int kk  = rest & 1; rest >>= 1;
  const int s   = rest % 36;
  const int map = rest / 36;
  const float* src = map ? w_cls : w_reg;
  const int g = s / 9, kp = s % 9;
  const int o = mf * 16 + (l & 15);
  const int cbase = kk * 32 + (l >> 4) * 8;
  union { ushort u[8]; short8v v; } hu, lu;
#pragma unroll
  for (int j = 0; j < 8; ++j) {
    const int c = cbase + j;
    const float v = src[o * 2304 + (g * 64 + c) * 9 + kp];
    const ushort h = f2bf(v);
    hu.u[j] = h;
    lu.u[j] = f2bf(v - bf2f(h));
  }
  const size_t eb = ((size_t)((map * 36 + s) * 2 + kk)) * 16384 + mf * 512 + l * 8;
  *reinterpret_cast<short8v*>(wpk + eb)        = hu.v;
  *reinterpret_cast<short8v*>(wpk + eb + 8192) = lu.v;
}

// ---------------------------------------------------------------------------
// Corner params for one (g,kp) step: 64 pixels (one image row).
// ---------------------------------------------------------------------------
__device__ __forceinline__ void calc_params(const float* __restrict__ off, int b,
                                            int px0, int t, int ss,
                                            int (*sIdx)[64][4], float (*sWt)[64][4],
                                            int bb) {
  const int hw = px0 + t;
  const int y = hw >> 6, x = hw & 63;
  const int kp = ss % 9;
  const float oy = off[((size_t)b * OC_ + 2 * ss) * HW_ + hw];
  const float ox = off[((size_t)b * OC_ + 2 * ss + 1) * HW_ + hw];
  const float py  = (float)(y + kp / 3 - 1) + oy;
  const float pxx = (float)(x + kp % 3 - 1) + ox;
  const float y0f = floorf(py), x0f = floorf(pxx);
  const float ty = py - y0f, tx = pxx - x0f;
  const int y0 = (int)y0f, x0 = (int)x0f;
  const int y1 = y0 + 1, x1 = x0 + 1;
  const bool vy0 = (y0 >= 0) & (y0 <= 63), vy1 = (y1 >= 0) & (y1 <= 63);
  const bool vx0 = (x0 >= 0) & (x0 <= 63), vx1 = (x1 >= 0) & (x1 <= 63);
  const int cy0 = min(max(y0, 0), 63), cy1 = min(max(y1, 0), 63);
  const int cx0 = min(max(x0, 0), 63), cx1 = min(max(x1, 0), 63);
  sIdx[bb][t][0] = cy0 * 64 + cx0; sWt[bb][t][0] = (vy0 && vx0) ? (1.f - ty) * (1.f - tx) : 0.f;
  sIdx[bb][t][1] = cy0 * 64 + cx1; sWt[bb][t][1] = (vy0 && vx1) ? (1.f - ty) * tx : 0.f;
  sIdx[bb][t][2] = cy1 * 64 + cx0; sWt[bb][t][2] = (vy1 && vx0) ? ty * (1.f - tx) : 0.f;
  sIdx[bb][t][3] = cy1 * 64 + cx1; sWt[bb][t][3] = (vy1 && vx1) ? ty * tx : 0.f;
}

// ---------------------------------------------------------------------------
// Kernel 3: MFMA implicit GEMM. Block = (map, b, image row): 256 Cout x 64 px.
// 4 waves, each 64(o) x 64(px). K = 2304, BK = 64 (one (g,kp) per step).
// A (weights) direct global->VGPR in fragment order; B (bilinear samples)
// computed into LDS in fragment order; 3-pass hi/lo bf16 split (~fp32 acc).
// ---------------------------------------------------------------------------
__global__ __launch_bounds__(256)
void deform_mfma(const float* __restrict__ xreg, const float* __restrict__ xcls,
                 const float* __restrict__ off, const ushort* __restrict__ wpk,
                 float* __restrict__ out) {
  __shared__ ushort Bh[4096];       // [kchunk2][nfrag4][lane64][j8]  8 KiB
  __shared__ ushort Bl[4096];       //                               8 KiB
  __shared__ int   sIdx[2][64][4];  // param double-buffer           2 KiB
  __shared__ float sWt[2][64][4];   //                               2 KiB

  // XCD-aware swizzle: 1024 blocks = 8 XCD x 128 contiguous (bijective).
  const int lin = blockIdx.y * 512 + blockIdx.x;
  const int nid = (lin & 7) * 128 + (lin >> 3);
  const int map = nid >> 9;
  const int nt  = nid & 511;
  const int b   = nt >> 6;
  const int px0 = (nt & 63) * 64;   // one image row per block

  const int t = threadIdx.x;
  const int lane = t & 63, wid = t >> 6;
  const float* xsrc = map ? xcls : xreg;

  f32x4 acc[4][4];
#pragma unroll
  for (int mf = 0; mf < 4; ++mf)
#pragma unroll
    for (int nf = 0; nf < 4; ++nf) acc[mf][nf] = (f32x4){0.f, 0.f, 0.f, 0.f};

  if (t < 64) calc_params(off, b, px0, t, 0, sIdx, sWt, 0);
  __syncthreads();

  for (int s = 0; s < 36; ++s) {
    const int pb = s & 1;
    const int g  = s / 9;

    // ---- A fragments: direct, coalesced global loads (L2/L3 resident) ----
    short8v a_h[2][4], a_l[2][4];
    const size_t abase = ((size_t)(map * 36 + s)) * 32768 + lane * 8;
#pragma unroll
    for (int kk = 0; kk < 2; ++kk)
#pragma unroll
      for (int mf = 0; mf < 4; ++mf) {
        const size_t e = abase + (size_t)kk * 16384 + (wid * 4 + mf) * 512;
        a_h[kk][mf] = *reinterpret_cast<const short8v*>(wpk + e);
        a_l[kk][mf] = *reinterpret_cast<const short8v*>(wpk + e + 8192);
      }

    // ---- produce B: 2 tasks/thread, 8 samples each, fragment-order write ----
    {
      const int px  = t & 63;
      const int kgb = t >> 6;
      const int i0 = sIdx[pb][px][0], i1 = sIdx[pb][px][1],
                i2 = sIdx[pb][px][2], i3 = sIdx[pb][px][3];
      const float w0 = sWt[pb][px][0], w1 = sWt[pb][px][1],
                  w2 = sWt[pb][px][2], w3 = sWt[pb][px][3];
#pragma unroll
      for (int q = 0; q < 2; ++q) {
        const int kg = kgb + q * 4;                 // 0..7: 8 channels each
        const float* xb = xsrc + ((size_t)((b * 4 + g) * 64 + kg * 8)) * HW_;
        union { ushort u[8]; short8v v; } hu, lu;
#pragma unroll
        for (int i = 0; i < 8; ++i) {
          const float* xc = xb + (size_t)i * HW_;
          const float v = w0 * xc[i0] + w1 * xc[i1] + w2 * xc[i2] + w3 * xc[i3];
          const ushort h = f2bf(v);
          hu.u[i] = h;
          lu.u[i] = f2bf(v - bf2f(h));
        }
        const int slot = ((kg >> 2) * 4 + (px >> 4)) * 64 + ((kg & 3) * 16 + (px & 15));
        *reinterpret_cast<short8v*>(Bh + slot * 8) = hu.v;
        *reinterpret_cast<short8v*>(Bl + slot * 8) = lu.v;
      }
    }

    // ---- params for next step (double-buffered) ----
    if (s + 1 < 36 && t < 64) calc_params(off, b, px0, t, s + 1, sIdx, sWt, pb ^ 1);
    __syncthreads();

    // ---- MFMA: 2 k-chunks x 4x4 frags x 3 passes (hh, hl, lh) ----
#pragma unroll
    for (int kk = 0; kk < 2; ++kk) {
      short8v bh[4], bl[4];
#pragma unroll
      for (int nf = 0; nf < 4; ++nf) {
        bh[nf] = *reinterpret_cast<const short8v*>(Bh + ((kk * 4 + nf) * 64 + lane) * 8);
        bl[nf] = *reinterpret_cast<const short8v*>(Bl + ((kk * 4 + nf) * 64 + lane) * 8);
      }
#pragma unroll
      for (int mf = 0; mf < 4; ++mf)
#pragma unroll
        for (int nf = 0; nf < 4; ++nf) {
          f32x4 c = acc[mf][nf];
          c = __builtin_amdgcn_mfma_f32_16x16x32_bf16(a_l[kk][mf], bh[nf], c, 0, 0, 0);
          c = __builtin_amdgcn_mfma_f32_16x16x32_bf16(a_h[kk][mf], bl[nf], c, 0, 0, 0);
          c = __builtin_amdgcn_mfma_f32_16x16x32_bf16(a_h[kk][mf], bh[nf], c, 0, 0, 0);
          acc[mf][nf] = c;
        }
    }
    __syncthreads();
  }

  // ---- epilogue: ReLU + store. D: row=(lane>>4)*4+r (o), col=lane&15 (px) ----
  float* obase = out + (map ? CLS_OFF : 0) + (size_t)b * C_ * HW_ + px0;
  const int m0 = wid * 64;
#pragma unroll
  for (int mf = 0; mf < 4; ++mf)
#pragma unroll
    for (int nf = 0; nf < 4; ++nf)
#pragma unroll
      for (int r = 0; r < 4; ++r) {
        const int o = m0 + mf * 16 + (lane >> 4) * 4 + r;
        const int n = nf * 16 + (lane & 15);
        obase[(size_t)o * HW_ + n] = fmaxf(acc[mf][nf][r], 0.f);
      }
}

// ---------------------------------------------------------------------------
extern "C" void kernel_launch(void* const* d_in, const int* in_sizes, int n_in,
                              void* d_out, int out_size, void* d_ws, size_t ws_size,
                              hipStream_t stream) {
  const float* reg_feat = (const float*)d_in[0];
  const float* cls_feat = (const float*)d_in[1];
  const float* pred     = (const float*)d_in[2];
  const float* w_off    = (const float*)d_in[3];
  const float* w_reg    = (const float*)d_in[4];
  const float* w_cls    = (const float*)d_in[5];
  float* outp = (float*)d_out;

  // ws: offset fp32 (9,437,184 B) | wpk bf16 hi/lo (4,718,592 B) = 14,155,776 B
  float*  offset = (float*)d_ws;
  ushort* wpk    = (ushort*)((char*)d_ws + (size_t)B_ * OC_ * HW_ * 4);

  offset_kernel<<<dim3((B_ * HW_) / 256), 256, 0, stream>>>(pred, w_off, offset);
  repack_w<<<dim3(576), 256, 0, stream>>>(w_reg, w_cls, wpk);
  deform_mfma<<<dim3(512, 2), dim3(256), 0, stream>>>(reg_feat, cls_feat,
                                                      offset, wpk, outp);
}

// Round 5
// 623.098 us; speedup vs baseline: 2.1639x; 1.0231x over previous
//
#include <hip/hip_runtime.h>

// Problem constants: B=8, C=256, H=W=64, dg=4, K=3x3.
#define B_   8
#define C_   256
#define HW_  4096
#define OC_  72      // offset channels = dg*2*9
#define PC_  34      // pred_init channels
#define CLS_OFF (B_ * C_ * HW_)

typedef __attribute__((ext_vector_type(8))) short short8v;  // 8 bf16 = 4 VGPR
typedef __attribute__((ext_vector_type(4))) float f32x4;

__device__ __forceinline__ ushort f2bf(float f) {           // fp32 -> bf16 RNE
  uint u = __float_as_uint(f);
  return (ushort)((u + 0x7fffu + ((u >> 16) & 1u)) >> 16);
}
__device__ __forceinline__ float bf2f(ushort h) {
  return __uint_as_float(((uint)h) << 16);
}

// ---------------------------------------------------------------------------
// Fused prep: blocks 0..127 = offset 1x1 conv; blocks 128..703 = weight
// repack into bf16 hi/lo MFMA-fragment order (layout verified in round 3):
// wpk[(map*36+s)*2+kk][hl][mf][lane][j]; o=mf*16+(l&15), c=kk*32+(l>>4)*8+j.
// ---------------------------------------------------------------------------
__global__ __launch_bounds__(256)
void prep_kernel(const float* __restrict__ pred, const float* __restrict__ wo,
                 const float* __restrict__ w_reg, const float* __restrict__ w_cls,
                 float* __restrict__ offset, ushort* __restrict__ wpk) {
  if (blockIdx.x < 128) {
    const int p  = blockIdx.x * 256 + threadIdx.x;
    const int b  = p >> 12;
    const int hw = p & 4095;
    const float* pp = pred + (size_t)b * PC_ * HW_ + hw;
    float v[PC_];
#pragma unroll
    for (int i = 0; i < PC_; ++i) v[i] = pp[(size_t)i * HW_];
    float* op = offset + (size_t)b * OC_ * HW_ + hw;
    for (int o = 0; o < OC_; ++o) {
      float s = 0.f;
#pragma unroll
      for (int i = 0; i < PC_; ++i) s = fmaf(v[i], wo[o * PC_ + i], s);
      op[(size_t)o * HW_] = s;
    }
  } else {
    const int tid = (blockIdx.x - 128) * 256 + threadIdx.x;
    const int l   = tid & 63;
    const int mf  = (tid >> 6) & 15;
    int rest = tid >> 10;
    const int kk  = rest & 1; rest >>= 1;
    const int s   = rest % 36;
    const int map = rest / 36;
    const float* src = map ? w_cls : w_reg;
    const int g = s / 9, kp = s % 9;
    const int o = mf * 16 + (l & 15);
    const int cbase = kk * 32 + (l >> 4) * 8;
    union { ushort u[8]; short8v v; } hu, lu;
#pragma unroll
    for (int j = 0; j < 8; ++j) {
      const int c = cbase + j;
      const float v = src[o * 2304 + (g * 64 + c) * 9 + kp];
      const ushort h = f2bf(v);
      hu.u[j] = h;
      lu.u[j] = f2bf(v - bf2f(h));
    }
    const size_t eb = ((size_t)((map * 36 + s) * 2 + kk)) * 16384 + mf * 512 + l * 8;
    *reinterpret_cast<short8v*>(wpk + eb)        = hu.v;
    *reinterpret_cast<short8v*>(wpk + eb + 8192) = lu.v;
  }
}

// ---------------------------------------------------------------------------
// Bilinear corner params for pixel (yy, xx) at step ss, from offset regs.
// ---------------------------------------------------------------------------
__device__ __forceinline__ void calcp(float oy, float ox, int ss, int yy, int xx,
                                      int& i0, int& i1, int& i2, int& i3,
                                      float& w0, float& w1, float& w2, float& w3) {
  const int kp = ss % 9;
  const float py  = (float)(yy + kp / 3 - 1) + oy;
  const float pxx = (float)(xx + kp % 3 - 1) + ox;
  const float y0f = floorf(py), x0f = floorf(pxx);
  const float ty = py - y0f, tx = pxx - x0f;
  const int y0 = (int)y0f, x0 = (int)x0f;
  const int y1 = y0 + 1, x1 = x0 + 1;
  const bool vy0 = (y0 >= 0) & (y0 <= 63), vy1 = (y1 >= 0) & (y1 <= 63);
  const bool vx0 = (x0 >= 0) & (x0 <= 63), vx1 = (x1 >= 0) & (x1 <= 63);
  const int cy0 = min(max(y0, 0), 63), cy1 = min(max(y1, 0), 63);
  const int cx0 = min(max(x0, 0), 63), cx1 = min(max(x1, 0), 63);
  i0 = cy0 * 64 + cx0;  w0 = (vy0 && vx0) ? (1.f - ty) * (1.f - tx) : 0.f;
  i1 = cy0 * 64 + cx1;  w1 = (vy0 && vx1) ? (1.f - ty) * tx         : 0.f;
  i2 = cy1 * 64 + cx0;  w2 = (vy1 && vx0) ? ty * (1.f - tx)         : 0.f;
  i3 = cy1 * 64 + cx1;  w3 = (vy1 && vx1) ? ty * tx                 : 0.f;
}

// ---------------------------------------------------------------------------
// MFMA implicit GEMM, software-pipelined:
// per step s: [issue A(s)] [params+gathers(s+1) -> regs] [MFMA(s) from LDS]
//             [convert+ds_write B(s+1) -> other buffer] [one barrier]
// Gather latency hides under 96 MFMAs; vmcnt never force-drained mid-loop.
// ---------------------------------------------------------------------------
__global__ __launch_bounds__(256, 2)
void deform_mfma(const float* __restrict__ xreg, const float* __restrict__ xcls,
                 const float* __restrict__ off, const ushort* __restrict__ wpk,
                 float* __restrict__ out) {
  __shared__ ushort Bh[2][4096];   // double-buffered B fragments   16 KiB
  __shared__ ushort Bl[2][4096];   //                               16 KiB

  // XCD-aware bijective swizzle: 1024 blocks = 8 XCD x 128 contiguous.
  const int lin = blockIdx.y * 512 + blockIdx.x;
  const int nid = (lin & 7) * 128 + (lin >> 3);
  const int map = nid >> 9;
  const int nt  = nid & 511;
  const int b   = nt >> 6;
  const int yy  = nt & 63;          // image row handled by this block
  const int px0 = yy * 64;

  const int t = threadIdx.x;
  const int lane = t & 63, wid = t >> 6;
  const int px = t & 63;            // this thread's sample pixel (x coord)
  const int kgb = wid;              // channel-octet 0..3
  const float* xsrc = map ? xcls : xreg;

  f32x4 acc[4][4];
#pragma unroll
  for (int mf = 0; mf < 4; ++mf)
#pragma unroll
    for (int nf = 0; nf < 4; ++nf) acc[mf][nf] = (f32x4){0.f, 0.f, 0.f, 0.f};

  const size_t obidx = ((size_t)b * OC_) * HW_ + px0 + px;  // + 2*ss*HW_ per step
  float offY = off[obidx];
  float offX = off[obidx + HW_];

  // ---- prologue: build B(0) into buffer 0 ----
  {
    int i0, i1, i2, i3; float w0, w1, w2, w3;
    calcp(offY, offX, 0, yy, px, i0, i1, i2, i3, w0, w1, w2, w3);
    const float* xb = xsrc + ((size_t)(b * 4 * 64 + kgb * 8)) * HW_;  // g=0
    float rc0[16], rc1[16], rc2[16], rc3[16];
#pragma unroll
    for (int q = 0; q < 2; ++q)
#pragma unroll
      for (int i = 0; i < 8; ++i) {
        const float* xc = xb + (size_t)(q * 32 + i) * HW_;
        rc0[q * 8 + i] = xc[i0]; rc1[q * 8 + i] = xc[i1];
        rc2[q * 8 + i] = xc[i2]; rc3[q * 8 + i] = xc[i3];
      }
    offY = off[obidx + 2 * HW_];    // prefetch offsets for step 1
    offX = off[obidx + 3 * HW_];
#pragma unroll
    for (int q = 0; q < 2; ++q) {
      union { ushort u[8]; short8v v; } hu, lu;
#pragma unroll
      for (int i = 0; i < 8; ++i) {
        const float v = w0 * rc0[q * 8 + i] + w1 * rc1[q * 8 + i]
                      + w2 * rc2[q * 8 + i] + w3 * rc3[q * 8 + i];
        const ushort h = f2bf(v);
        hu.u[i] = h; lu.u[i] = f2bf(v - bf2f(h));
      }
      const int slot = (q * 4 + (px >> 4)) * 64 + kgb * 16 + (px & 15);
      *reinterpret_cast<short8v*>(&Bh[0][slot * 8]) = hu.v;
      *reinterpret_cast<short8v*>(&Bl[0][slot * 8]) = lu.v;
    }
  }
  __syncthreads();

  // ---- main loop ----
  for (int s = 0; s < 36; ++s) {
    const int cb = s & 1, nb = cb ^ 1;

    // A(s) fragments: issued FIRST (oldest) so their counted wait at the
    // MFMAs doesn't drain the gather queue behind them.
    short8v a_h[2][4], a_l[2][4];
    const size_t abase = ((size_t)(map * 36 + s)) * 32768 + (size_t)lane * 8;
#pragma unroll
    for (int kk = 0; kk < 2; ++kk)
#pragma unroll
      for (int mf = 0; mf < 4; ++mf) {
        const size_t e = abase + (size_t)kk * 16384 + (size_t)(wid * 4 + mf) * 512;
        a_h[kk][mf] = *reinterpret_cast<const short8v*>(wpk + e);
        a_l[kk][mf] = *reinterpret_cast<const short8v*>(wpk + e + 8192);
      }

    // Gathers for step s+1 -> registers (latency covered by MFMA(s)).
    int i0, i1, i2, i3; float w0, w1, w2, w3;
    float rc0[16], rc1[16], rc2[16], rc3[16];
    if (s < 35) {
      calcp(offY, offX, s + 1, yy, px, i0, i1, i2, i3, w0, w1, w2, w3);
      const int g1 = (s + 1) / 9;
      const float* xb = xsrc + ((size_t)((b * 4 + g1) * 64 + kgb * 8)) * HW_;
#pragma unroll
      for (int q = 0; q < 2; ++q)
#pragma unroll
        for (int i = 0; i < 8; ++i) {
          const float* xc = xb + (size_t)(q * 32 + i) * HW_;
          rc0[q * 8 + i] = xc[i0]; rc1[q * 8 + i] = xc[i1];
          rc2[q * 8 + i] = xc[i2]; rc3[q * 8 + i] = xc[i3];
        }
      if (s < 34) {                 // prefetch offsets for step s+2
        offY = off[obidx + (size_t)(2 * s + 4) * HW_];
        offX = off[obidx + (size_t)(2 * s + 5) * HW_];
      }
    }

    // ---- MFMA(s): 2 k-chunks x 4x4 frags x 3 passes ----
    __builtin_amdgcn_s_setprio(1);
#pragma unroll
    for (int kk = 0; kk < 2; ++kk)
#pragma unroll
      for (int nf = 0; nf < 4; ++nf) {
        const short8v bh = *reinterpret_cast<const short8v*>(&Bh[cb][((kk * 4 + nf) * 64 + lane) * 8]);
        const short8v bl = *reinterpret_cast<const short8v*>(&Bl[cb][((kk * 4 + nf) * 64 + lane) * 8]);
#pragma unroll
        for (int mf = 0; mf < 4; ++mf) {
          f32x4 c = acc[mf][nf];
          c = __builtin_amdgcn_mfma_f32_16x16x32_bf16(a_l[kk][mf], bh, c, 0, 0, 0);
          c = __builtin_amdgcn_mfma_f32_16x16x32_bf16(a_h[kk][mf], bl, c, 0, 0, 0);
          c = __builtin_amdgcn_mfma_f32_16x16x32_bf16(a_h[kk][mf], bh, c, 0, 0, 0);
          acc[mf][nf] = c;
        }
      }
    __builtin_amdgcn_s_setprio(0);

    // ---- convert + write B(s+1) into the other buffer ----
    if (s < 35) {
#pragma unroll
      for (int q = 0; q < 2; ++q) {
        union { ushort u[8]; short8v v; } hu, lu;
#pragma unroll
        for (int i = 0; i < 8; ++i) {
          const float v = w0 * rc0[q * 8 + i] + w1 * rc1[q * 8 + i]
                        + w2 * rc2[q * 8 + i] + w3 * rc3[q * 8 + i];
          const ushort h = f2bf(v);
          hu.u[i] = h; lu.u[i] = f2bf(v - bf2f(h));
        }
        const int slot = (q * 4 + (px >> 4)) * 64 + kgb * 16 + (px & 15);
        *reinterpret_cast<short8v*>(&Bh[nb][slot * 8]) = hu.v;
        *reinterpret_cast<short8v*>(&Bl[nb][slot * 8]) = lu.v;
      }
    }
    __syncthreads();
  }

  // ---- epilogue: ReLU + store. D: row=(lane>>4)*4+r, col=lane&15 ----
  float* obase = out + (map ? CLS_OFF : 0) + (size_t)b * C_ * HW_ + px0;
  const int m0 = wid * 64;
#pragma unroll
  for (int mf = 0; mf < 4; ++mf)
#pragma unroll
    for (int nf = 0; nf < 4; ++nf)
#pragma unroll
      for (int r = 0; r < 4; ++r) {
        const int o = m0 + mf * 16 + (lane >> 4) * 4 + r;
        const int n = nf * 16 + (lane & 15);
        obase[(size_t)o * HW_ + n] = fmaxf(acc[mf][nf][r], 0.f);
      }
}

// ---------------------------------------------------------------------------
extern "C" void kernel_launch(void* const* d_in, const int* in_sizes, int n_in,
                              void* d_out, int out_size, void* d_ws, size_t ws_size,
                              hipStream_t stream) {
  const float* reg_feat = (const float*)d_in[0];
  const float* cls_feat = (const float*)d_in[1];
  const float* pred     = (const float*)d_in[2];
  const float* w_off    = (const float*)d_in[3];
  const float* w_reg    = (const float*)d_in[4];
  const float* w_cls    = (const float*)d_in[5];
  float* outp = (float*)d_out;

  // ws: offset fp32 (9,437,184 B) | wpk bf16 hi/lo (4,718,592 B)
  float*  offset = (float*)d_ws;
  ushort* wpk    = (ushort*)((char*)d_ws + (size_t)B_ * OC_ * HW_ * 4);

  prep_kernel<<<dim3(704), 256, 0, stream>>>(pred, w_off, w_reg, w_cls,
                                             offset, wpk);
  deform_mfma<<<dim3(512, 2), dim3(256), 0, stream>>>(reg_feat, cls_feat,
                                                      offset, wpk, outp);
}

// Round 6
// 598.063 us; speedup vs baseline: 2.2545x; 1.0419x over previous
//
#include <hip/hip_runtime.h>
#include <hip/hip_bf16.h>

// Problem constants: B=8, C=256, H=W=64, dg=4, K=3x3.
#define B_   8
#define C_   256
#define HW_  4096
#define OC_  72      // offset channels = dg*2*9
#define PC_  34      // pred_init channels
#define CLS_OFF (B_ * C_ * HW_)

typedef __attribute__((ext_vector_type(8))) short short8v;  // 8 bf16 = 4 VGPR
typedef __attribute__((ext_vector_type(4))) float f32x4;

__device__ __forceinline__ ushort f2bf(float f) {           // fp32 -> bf16 RNE
  uint u = __float_as_uint(f);
  return (ushort)((u + 0x7fffu + ((u >> 16) & 1u)) >> 16);
}
__device__ __forceinline__ float bf2f(ushort h) {
  return __uint_as_float(((uint)h) << 16);
}
// Packed pair conversion: low16 = bf16(v0), high16 = bf16(v1), RNE.
__device__ __forceinline__ uint pk2(float v0, float v1) {
  union { __hip_bfloat162 b; uint u; } c;
  c.b = __float22bfloat162_rn(float2{v0, v1});
  return c.u;
}

// ---------------------------------------------------------------------------
// Fused prep: blocks 0..127 = offset 1x1 conv; blocks 128..703 = weight
// repack into bf16 hi/lo MFMA-fragment order (layout verified round 3/5):
// wpk[(map*36+s)*2+kk][hl][mf][lane][j]; o=mf*16+(l&15), c=kk*32+(l>>4)*8+j.
// ---------------------------------------------------------------------------
__global__ __launch_bounds__(256)
void prep_kernel(const float* __restrict__ pred, const float* __restrict__ wo,
                 const float* __restrict__ w_reg, const float* __restrict__ w_cls,
                 float* __restrict__ offset, ushort* __restrict__ wpk) {
  if (blockIdx.x < 128) {
    const int p  = blockIdx.x * 256 + threadIdx.x;
    const int b  = p >> 12;
    const int hw = p & 4095;
    const float* pp = pred + (size_t)b * PC_ * HW_ + hw;
    float v[PC_];
#pragma unroll
    for (int i = 0; i < PC_; ++i) v[i] = pp[(size_t)i * HW_];
    float* op = offset + (size_t)b * OC_ * HW_ + hw;
    for (int o = 0; o < OC_; ++o) {
      float s = 0.f;
#pragma unroll
      for (int i = 0; i < PC_; ++i) s = fmaf(v[i], wo[o * PC_ + i], s);
      op[(size_t)o * HW_] = s;
    }
  } else {
    const int tid = (blockIdx.x - 128) * 256 + threadIdx.x;
    const int l   = tid & 63;
    const int mf  = (tid >> 6) & 15;
    int rest = tid >> 10;
    const int kk  = rest & 1; rest >>= 1;
    const int s   = rest % 36;
    const int map = rest / 36;
    const float* src = map ? w_cls : w_reg;
    const int g = s / 9, kp = s % 9;
    const int o = mf * 16 + (l & 15);
    const int cbase = kk * 32 + (l >> 4) * 8;
    union { ushort u[8]; short8v v; } hu, lu;
#pragma unroll
    for (int j = 0; j < 8; ++j) {
      const int c = cbase + j;
      const float v = src[o * 2304 + (g * 64 + c) * 9 + kp];
      const ushort h = f2bf(v);
      hu.u[j] = h;
      lu.u[j] = f2bf(v - bf2f(h));
    }
    const size_t eb = ((size_t)((map * 36 + s) * 2 + kk)) * 16384 + mf * 512 + l * 8;
    *reinterpret_cast<short8v*>(wpk + eb)        = hu.v;
    *reinterpret_cast<short8v*>(wpk + eb + 8192) = lu.v;
  }
}

// ---------------------------------------------------------------------------
// Bilinear corner params for pixel (yy, xx) at step ss, from offset regs.
// ---------------------------------------------------------------------------
__device__ __forceinline__ void calcp(float oy, float ox, int ss, int yy, int xx,
                                      int& i0, int& i1, int& i2, int& i3,
                                      float& w0, float& w1, float& w2, float& w3) {
  const int kp = ss % 9;
  const float py  = (float)(yy + kp / 3 - 1) + oy;
  const float pxx = (float)(xx + kp % 3 - 1) + ox;
  const float y0f = floorf(py), x0f = floorf(pxx);
  const float ty = py - y0f, tx = pxx - x0f;
  const int y0 = (int)y0f, x0 = (int)x0f;
  const int y1 = y0 + 1, x1 = x0 + 1;
  const bool vy0 = (y0 >= 0) & (y0 <= 63), vy1 = (y1 >= 0) & (y1 <= 63);
  const bool vx0 = (x0 >= 0) & (x0 <= 63), vx1 = (x1 >= 0) & (x1 <= 63);
  const int cy0 = min(max(y0, 0), 63), cy1 = min(max(y1, 0), 63);
  const int cx0 = min(max(x0, 0), 63), cx1 = min(max(x1, 0), 63);
  i0 = cy0 * 64 + cx0;  w0 = (vy0 && vx0) ? (1.f - ty) * (1.f - tx) : 0.f;
  i1 = cy0 * 64 + cx1;  w1 = (vy0 && vx1) ? (1.f - ty) * tx         : 0.f;
  i2 = cy1 * 64 + cx0;  w2 = (vy1 && vx0) ? ty * (1.f - tx)         : 0.f;
  i3 = cy1 * 64 + cx1;  w3 = (vy1 && vx1) ? ty * tx                 : 0.f;
}

// ---------------------------------------------------------------------------
// MFMA implicit GEMM, TLP-oriented (no cross-step reg pipeline):
// per step s: [params] [gather 4ch-batches -> convert(pk) -> ds_write]
//             [barrier] [kk-split MFMA: A half-loads (32 VGPR)] [barrier]
// Registers ~150 -> 3 waves/SIMD (launch_bounds(256,3)); 12 waves/CU hide
// the gather/A-load latency across 3 unsynchronized blocks.
// ---------------------------------------------------------------------------
__global__ __launch_bounds__(256, 3)
void deform_mfma(const float* __restrict__ xreg, const float* __restrict__ xcls,
                 const float* __restrict__ off, const ushort* __restrict__ wpk,
                 float* __restrict__ out) {
  __shared__ ushort Bh[4096];   // B fragments, hi   8 KiB
  __shared__ ushort Bl[4096];   // B fragments, lo   8 KiB

  // XCD-aware bijective swizzle: 1024 blocks = 8 XCD x 128 contiguous.
  const int lin = blockIdx.y * 512 + blockIdx.x;
  const int nid = (lin & 7) * 128 + (lin >> 3);
  const int map = nid >> 9;
  const int nt  = nid & 511;
  const int b   = nt >> 6;
  const int yy  = nt & 63;          // image row handled by this block
  const int px0 = yy * 64;

  const int t = threadIdx.x;
  const int lane = t & 63, wid = t >> 6;
  const int px = t & 63;            // this thread's sample pixel (x coord)
  const int kgb = wid;              // channel-octet 0..3
  const float* xsrc = map ? xcls : xreg;

  f32x4 acc[4][4];
#pragma unroll
  for (int mf = 0; mf < 4; ++mf)
#pragma unroll
    for (int nf = 0; nf < 4; ++nf) acc[mf][nf] = (f32x4){0.f, 0.f, 0.f, 0.f};

  const size_t obidx = ((size_t)b * OC_) * HW_ + px0 + px;
  float offY = off[obidx];
  float offX = off[obidx + HW_];

  for (int s = 0; s < 36; ++s) {
    // ---- bilinear params (per-thread, from prefetched offsets) ----
    int i0, i1, i2, i3; float w0, w1, w2, w3;
    calcp(offY, offX, s, yy, px, i0, i1, i2, i3, w0, w1, w2, w3);

    const int g = s / 9;
    const float* xb = xsrc + ((size_t)((b * 4 + g) * 64 + kgb * 8)) * HW_;

    __syncthreads();   // WAR: all waves done reading B from step s-1

    // ---- gather + convert + write B, 4-channel batches (16 regs in flight) --
#pragma unroll
    for (int q = 0; q < 2; ++q) {
      const float* xq = xb + (size_t)q * 32 * HW_;
      const int slot = (q * 4 + (px >> 4)) * 64 + kgb * 16 + (px & 15);
#pragma unroll
      for (int h = 0; h < 2; ++h) {
        float r0[4], r1[4], r2[4], r3[4];
#pragma unroll
        for (int i = 0; i < 4; ++i) {
          const float* xc = xq + (size_t)(h * 4 + i) * HW_;
          r0[i] = xc[i0]; r1[i] = xc[i1]; r2[i] = xc[i2]; r3[i] = xc[i3];
        }
        uint hh[2], ll[2];
#pragma unroll
        for (int p = 0; p < 2; ++p) {
          const float v0 = fmaf(w0, r0[2 * p],     fmaf(w1, r1[2 * p],     fmaf(w2, r2[2 * p],     w3 * r3[2 * p])));
          const float v1 = fmaf(w0, r0[2 * p + 1], fmaf(w1, r1[2 * p + 1], fmaf(w2, r2[2 * p + 1], w3 * r3[2 * p + 1])));
          const uint hu = pk2(v0, v1);
          const float l0 = v0 - __uint_as_float(hu << 16);
          const float l1 = v1 - __uint_as_float(hu & 0xffff0000u);
          hh[p] = hu;
          ll[p] = pk2(l0, l1);
        }
        *reinterpret_cast<uint2*>(&Bh[slot * 8 + h * 4]) = make_uint2(hh[0], hh[1]);
        *reinterpret_cast<uint2*>(&Bl[slot * 8 + h * 4]) = make_uint2(ll[0], ll[1]);
      }
    }

    // prefetch next step's offsets (in flight across barrier + MFMA)
    if (s < 35) {
      offY = off[obidx + (size_t)(2 * s + 2) * HW_];
      offX = off[obidx + (size_t)(2 * s + 3) * HW_];
    }

    __syncthreads();   // B(s) visible to all waves

    // ---- MFMA: kk-split halves (A = 32 VGPR live), 3-pass hi/lo ----
    __builtin_amdgcn_s_setprio(1);
#pragma unroll
    for (int kk = 0; kk < 2; ++kk) {
      short8v a_h[4], a_l[4];
      const size_t abase = ((size_t)(map * 36 + s)) * 32768
                         + (size_t)kk * 16384 + (size_t)lane * 8;
#pragma unroll
      for (int mf = 0; mf < 4; ++mf) {
        const size_t e = abase + (size_t)(wid * 4 + mf) * 512;
        a_h[mf] = *reinterpret_cast<const short8v*>(wpk + e);
        a_l[mf] = *reinterpret_cast<const short8v*>(wpk + e + 8192);
      }
#pragma unroll
      for (int nf = 0; nf < 4; ++nf) {
        const short8v bh = *reinterpret_cast<const short8v*>(&Bh[((kk * 4 + nf) * 64 + lane) * 8]);
        const short8v bl = *reinterpret_cast<const short8v*>(&Bl[((kk * 4 + nf) * 64 + lane) * 8]);
#pragma unroll
        for (int mf = 0; mf < 4; ++mf) {
          f32x4 c = acc[mf][nf];
          c = __builtin_amdgcn_mfma_f32_16x16x32_bf16(a_l[mf], bh, c, 0, 0, 0);
          c = __builtin_amdgcn_mfma_f32_16x16x32_bf16(a_h[mf], bl, c, 0, 0, 0);
          c = __builtin_amdgcn_mfma_f32_16x16x32_bf16(a_h[mf], bh, c, 0, 0, 0);
          acc[mf][nf] = c;
        }
      }
    }
    __builtin_amdgcn_s_setprio(0);
  }

  // ---- epilogue: ReLU + store. D: row=(lane>>4)*4+r, col=lane&15 ----
  float* obase = out + (map ? CLS_OFF : 0) + (size_t)b * C_ * HW_ + px0;
  const int m0 = wid * 64;
#pragma unroll
  for (int mf = 0; mf < 4; ++mf)
#pragma unroll
    for (int nf = 0; nf < 4; ++nf)
#pragma unroll
      for (int r = 0; r < 4; ++r) {
        const int o = m0 + mf * 16 + (lane >> 4) * 4 + r;
        const int n = nf * 16 + (lane & 15);
        obase[(size_t)o * HW_ + n] = fmaxf(acc[mf][nf][r], 0.f);
      }
}

// ---------------------------------------------------------------------------
extern "C" void kernel_launch(void* const* d_in, const int* in_sizes, int n_in,
                              void* d_out, int out_size, void* d_ws, size_t ws_size,
                              hipStream_t stream) {
  const float* reg_feat = (const float*)d_in[0];
  const float* cls_feat = (const float*)d_in[1];
  const float* pred     = (const float*)d_in[2];
  const float* w_off    = (const float*)d_in[3];
  const float* w_reg    = (const float*)d_in[4];
  const float* w_cls    = (const float*)d_in[5];
  float* outp = (float*)d_out;

  // ws: offset fp32 (9,437,184 B) | wpk bf16 hi/lo (4,718,592 B)
  float*  offset = (float*)d_ws;
  ushort* wpk    = (ushort*)((char*)d_ws + (size_t)B_ * OC_ * HW_ * 4);

  prep_kernel<<<dim3(704), 256, 0, stream>>>(pred, w_off, w_reg, w_cls,
                                             offset, wpk);
  deform_mfma<<<dim3(512, 2), dim3(256), 0, stream>>>(reg_feat, cls_feat,
                                                      offset, wpk, outp);
}